// Round 3
// baseline (247.120 us; speedup 1.0000x reference)
//
#include <hip/hip_runtime.h>
#include <hip/hip_bf16.h>
#include <stdint.h>

// Problem constants
#define BB 8
#define SS 2048
#define NEXP 16
#define DIN 1024
#define DOUT 1024

typedef short bf16x8 __attribute__((ext_vector_type(8)));
typedef float floatx4 __attribute__((ext_vector_type(4)));

// fp32 -> bf16 round-to-nearest-even (bit trick; inputs are normal floats)
__device__ __forceinline__ unsigned short f2bf(float f) {
    union { float f; unsigned int u; } v; v.f = f;
    unsigned int u = v.u;
    unsigned int r = u + 0x7FFFu + ((u >> 16) & 1u);
    return (unsigned short)(r >> 16);
}

// 2x fp32 -> packed bf16x2 (hardware v_cvt_pk_bf16_f32, RNE)
__device__ __forceinline__ unsigned pk2(float a, float b) {
    __hip_bfloat162 h = __float22bfloat162_rn(float2{a, b});
    union { __hip_bfloat162 h; unsigned u; } cv; cv.h = h;
    return cv.u;
}

// async global->LDS, 16B per lane. LDS dest = wave-uniform base + lane*16.
__device__ __forceinline__ void gload16(const void* g, void* l) {
    __builtin_amdgcn_global_load_lds(
        (const __attribute__((address_space(1))) void*)g,
        (__attribute__((address_space(3))) void*)l,
        16, 0, 0);
}

// ---------------------------------------------------------------------------
// Kernel 1 (prep) — R6: xconv DELETED (fused into gemm A-staging).
// R5 post-mortem: prep stuck at 57us / ~2.07 TB/s across THREE block layouts
// (occ 33% and 64% identical time) -> not latency-bound; that's what the
// mixed stream sustains. Fix: remove 96 MB of the traffic (x read + xb write)
// by converting fp32->bf16 inside gemm's staging. Prep is now just:
//   [0,2048):    weight mix (2 cols/thread, float2, all 8 batches, VGPR 32)
//   [2048,2080): bias mix
// Traffic: 64 MB w read (L3-resident across iters) + 16.4 MB write.
// ---------------------------------------------------------------------------
__global__ __launch_bounds__(256) void prep_kernel(
    const float* __restrict__ p, const float* __restrict__ w,
    const float* __restrict__ bias,
    unsigned short* __restrict__ mw, float* __restrict__ mb)
{
    const int tid = threadIdx.x;
    const int blk = blockIdx.x;

    if (blk < 2048) {                       // ---- weight mix ----
        __shared__ float sp[BB * NEXP];
        if (tid < BB * NEXP) sp[tid] = p[tid];
        __syncthreads();
        const long t  = (long)blk * 256 + tid;      // 0..524287
        const long j2 = t * 2;                      // column pair
        float acc[BB][2];
        #pragma unroll
        for (int b = 0; b < BB; ++b) { acc[b][0] = 0.f; acc[b][1] = 0.f; }
        #pragma unroll
        for (int n = 0; n < NEXP; ++n) {
            float2 wv = *(const float2*)(w + (long)n * DOUT * DIN + j2);
            #pragma unroll
            for (int b = 0; b < BB; ++b) {
                float pb = sp[b * NEXP + n];
                acc[b][0] += pb * wv.x; acc[b][1] += pb * wv.y;
            }
        }
        #pragma unroll
        for (int b = 0; b < BB; ++b) {
            unsigned o = (unsigned)f2bf(acc[b][0]) | ((unsigned)f2bf(acc[b][1]) << 16);
            *(unsigned*)(mw + (long)b * DOUT * DIN + j2) = o;
        }
    } else {                                // ---- bias mix (tiny) ----
        const long t = (long)(blk - 2048) * 256 + tid;    // 0..8191
        const int b = (int)(t >> 10), i = (int)(t & 1023);
        float s = 0.f;
        #pragma unroll
        for (int n = 0; n < NEXP; ++n) s += p[b * NEXP + n] * bias[n * DOUT + i];
        mb[t] = s;
    }
}

// ---------------------------------------------------------------------------
// Kernel 2: batched GEMM  out[b] = cvt_bf16(x[b]) (S x K) * mixed_w[b]^T + mb[b]
// R6 change: A-tile staged from fp32 x with in-flight bf16 convert:
//   per chunk: 2x global_load_dwordx4 (fp32, pre-swizzled source column)
//              -> 4x v_cvt_pk_bf16_f32 -> 1x ds_write_b128.
//   LDS layout and the MFMA read path are IDENTICAL to before (same XOR
//   swizzle), only the producer changed. B stays on global_load_lds.
// Grid = (B, N, M): linear id % 8 == b -> per-XCD L2; x M-slice (512 KB fp32)
// reused x8 across tileN blocks inside one XCD's 4MB L2 -> x HBM read ~64MB once.
// ---------------------------------------------------------------------------
__global__ __launch_bounds__(256) void gemm_kernel(
    const float* __restrict__ x,             // [B][S][DIN] fp32
    const unsigned short* __restrict__ mw,   // [B][DOUT][DIN] bf16
    const float* __restrict__ mb,            // [B][DOUT] fp32
    float* __restrict__ out)                 // [B][S][DOUT] fp32
{
    __shared__ __align__(16) unsigned short sA[128 * 64];  // 16 KB
    __shared__ __align__(16) unsigned short sB[128 * 64];  // 16 KB

    const int tid  = threadIdx.x;
    const int wave = tid >> 6;
    const int lane = tid & 63;
    const int b    = blockIdx.x;          // batch -> XCD (id % 8 == b)
    const int tileN = blockIdx.y * 128;   // over DOUT
    const int tileM = blockIdx.z * 128;   // over S

    const float*          Ag = x  + (long)b * SS * DIN;
    const unsigned short* Bg = mw + (long)b * DOUT * DIN;

    const int q     = lane >> 4;     // quad 0..3
    const int r16   = lane & 15;
    const int mBase = 64 * (wave >> 1);
    const int nBase = 64 * (wave & 1);

    // staging: each wave owns 4 chunks of 8 rows x 64 cols for A and B
    const int sRow   = lane >> 3;                    // 0..7 row within chunk
    const int sColSw = (((lane & 7) ^ sRow) * 8);    // XOR-swizzled source column

    // hoisted loop-invariant source/dest addresses
    const float* aSrc[4]; const unsigned short* bSrc[4];
    unsigned short* aDst[4]; unsigned short* bDst[4];
    #pragma unroll
    for (int c = 0; c < 4; ++c) {
        const int chunk = wave * 4 + c;              // 0..15
        const int row   = chunk * 8 + sRow;          // 0..127
        aSrc[c] = Ag + (long)(tileM + row) * DIN + sColSw;
        bSrc[c] = Bg + (long)(tileN + row) * DIN + sColSw;
        aDst[c] = &sA[chunk * 512 + lane * 8];       // explicit per-lane 16B slot
        bDst[c] = &sB[chunk * 512];                  // gload_lds: wave base + lane*16
    }

    // reader: XOR-swizzled 16B-group offsets for the two kk halves (invariant)
    const int swz  = r16 & 7;
    const int colK0 = ((q)     ^ swz) * 8;           // kk = 0..31  (group q)
    const int colK1 = ((q + 4) ^ swz) * 8;           // kk = 32..63 (group q+4)

    floatx4 acc[4][4];
    #pragma unroll
    for (int mi = 0; mi < 4; ++mi)
        #pragma unroll
        for (int ni = 0; ni < 4; ++ni)
            acc[mi][ni] = (floatx4){0.f, 0.f, 0.f, 0.f};

    #pragma unroll
    for (int t = 0; t < 16; ++t) {                   // k0 = 64*t, fully unrolled
        __syncthreads();   // previous tile's compute done before overwrite

        // B: async global->LDS (imm offset 128*t bytes <= 1920)
        #pragma unroll
        for (int c = 0; c < 4; ++c)
            gload16(bSrc[c] + 64 * t, bDst[c]);

        // A: fp32 load -> cvt_pk bf16 -> ds_write (imm offsets 256*t, +16)
        #pragma unroll
        for (int c = 0; c < 4; ++c) {
            float4 u = *(const float4*)(aSrc[c] + 64 * t);
            float4 v = *(const float4*)(aSrc[c] + 64 * t + 4);
            uint4 o;
            o.x = pk2(u.x, u.y); o.y = pk2(u.z, u.w);
            o.z = pk2(v.x, v.y); o.w = pk2(v.z, v.w);
            *(uint4*)aDst[c] = o;
        }

        __syncthreads();   // loads + ds_writes visible

        #pragma unroll
        for (int kh = 0; kh < 2; ++kh) {
            const int col = kh ? colK1 : colK0;
            bf16x8 af[4], bfv[4];
            #pragma unroll
            for (int i = 0; i < 4; ++i)
                af[i] = *(const bf16x8*)&sA[(mBase + 16 * i + r16) * 64 + col];
            #pragma unroll
            for (int i = 0; i < 4; ++i)
                bfv[i] = *(const bf16x8*)&sB[(nBase + 16 * i + r16) * 64 + col];
            #pragma unroll
            for (int mi = 0; mi < 4; ++mi)
                #pragma unroll
                for (int ni = 0; ni < 4; ++ni)
                    acc[mi][ni] = __builtin_amdgcn_mfma_f32_16x16x32_bf16(
                        af[mi], bfv[ni], acc[mi][ni], 0, 0, 0);
        }
    }

    // epilogue: C[m][n] = acc + mixed_b[b][n]
    float bv[4];
    #pragma unroll
    for (int ni = 0; ni < 4; ++ni)
        bv[ni] = mb[b * DOUT + tileN + nBase + 16 * ni + r16];

    #pragma unroll
    for (int mi = 0; mi < 4; ++mi) {
        #pragma unroll
        for (int rr = 0; rr < 4; ++rr) {
            const int row = tileM + mBase + 16 * mi + q * 4 + rr;
            float* orow = out + (long)b * SS * DOUT + (long)row * DOUT;
            #pragma unroll
            for (int ni = 0; ni < 4; ++ni)
                orow[tileN + nBase + 16 * ni + r16] = acc[mi][ni][rr] + bv[ni];
        }
    }
}

extern "C" void kernel_launch(void* const* d_in, const int* in_sizes, int n_in,
                              void* d_out, int out_size, void* d_ws, size_t ws_size,
                              hipStream_t stream) {
    const float* x    = (const float*)d_in[0];   // [8,2048,1024]
    const float* p    = (const float*)d_in[1];   // [8,16]
    const float* w    = (const float*)d_in[2];   // [16,1024,1024]
    const float* bias = (const float*)d_in[3];   // [16,1024]
    float* out = (float*)d_out;                  // [8,2048,1024]

    // workspace layout: mixed_w bf16 (16 MiB) | mixed_b fp32 (32 KiB)
    unsigned short* mw = (unsigned short*)d_ws;
    float*          mb = (float*)((char*)d_ws + (size_t)16777216);

    prep_kernel<<<dim3(2080), 256, 0, stream>>>(p, w, bias, mw, mb);

    dim3 ggrid(BB, DOUT / 128, SS / 128);        // (8,8,16) = 1024 blocks
    gemm_kernel<<<ggrid, 256, 0, stream>>>(x, mw, mb, out);
}

// Round 4
// 224.938 us; speedup vs baseline: 1.0986x; 1.0986x over previous
//
#include <hip/hip_runtime.h>
#include <hip/hip_bf16.h>
#include <stdint.h>

// Problem constants
#define BB 8
#define SS 2048
#define NEXP 16
#define DIN 1024
#define DOUT 1024

typedef short bf16x8 __attribute__((ext_vector_type(8)));
typedef float floatx4 __attribute__((ext_vector_type(4)));

// fp32 -> bf16 round-to-nearest-even (bit trick; inputs are normal floats)
__device__ __forceinline__ unsigned short f2bf(float f) {
    union { float f; unsigned int u; } v; v.f = f;
    unsigned int u = v.u;
    unsigned int r = u + 0x7FFFu + ((u >> 16) & 1u);
    return (unsigned short)(r >> 16);
}

// 2x fp32 -> packed bf16x2 (hardware v_cvt_pk_bf16_f32, RNE)
__device__ __forceinline__ unsigned pk2(float a, float b) {
    __hip_bfloat162 h = __float22bfloat162_rn(float2{a, b});
    union { __hip_bfloat162 h; unsigned u; } cv; cv.h = h;
    return cv.u;
}

// async global->LDS, 16B per lane. LDS dest = wave-uniform base + lane*16.
__device__ __forceinline__ void gload16(const void* g, void* l) {
    __builtin_amdgcn_global_load_lds(
        (const __attribute__((address_space(1))) void*)g,
        (__attribute__((address_space(3))) void*)l,
        16, 0, 0);
}

// ---------------------------------------------------------------------------
// Kernel 1 (prep): wmix + bias only (~15 us by wall algebra: wall ~= 2x kernel
// sum across R0-R6). xconv deleted in R6, fused into gemm A-staging.
// ---------------------------------------------------------------------------
__global__ __launch_bounds__(256) void prep_kernel(
    const float* __restrict__ p, const float* __restrict__ w,
    const float* __restrict__ bias,
    unsigned short* __restrict__ mw, float* __restrict__ mb)
{
    const int tid = threadIdx.x;
    const int blk = blockIdx.x;

    if (blk < 2048) {                       // ---- weight mix ----
        __shared__ float sp[BB * NEXP];
        if (tid < BB * NEXP) sp[tid] = p[tid];
        __syncthreads();
        const long t  = (long)blk * 256 + tid;      // 0..524287
        const long j2 = t * 2;                      // column pair
        float acc[BB][2];
        #pragma unroll
        for (int b = 0; b < BB; ++b) { acc[b][0] = 0.f; acc[b][1] = 0.f; }
        #pragma unroll
        for (int n = 0; n < NEXP; ++n) {
            float2 wv = *(const float2*)(w + (long)n * DOUT * DIN + j2);
            #pragma unroll
            for (int b = 0; b < BB; ++b) {
                float pb = sp[b * NEXP + n];
                acc[b][0] += pb * wv.x; acc[b][1] += pb * wv.y;
            }
        }
        #pragma unroll
        for (int b = 0; b < BB; ++b) {
            unsigned o = (unsigned)f2bf(acc[b][0]) | ((unsigned)f2bf(acc[b][1]) << 16);
            *(unsigned*)(mw + (long)b * DOUT * DIN + j2) = o;
        }
    } else {                                // ---- bias mix (tiny) ----
        const long t = (long)(blk - 2048) * 256 + tid;    // 0..8191
        const int b = (int)(t >> 10), i = (int)(t & 1023);
        float s = 0.f;
        #pragma unroll
        for (int n = 0; n < NEXP; ++n) s += p[b * NEXP + n] * bias[n * DOUT + i];
        mb[t] = s;
    }
}

// ---------------------------------------------------------------------------
// Kernel 2: batched GEMM  out[b] = cvt_bf16(x[b]) (S x K) * mixed_w[b]^T + mb[b]
// R7: fix R6's serialization (gemm 48->108us, MfmaUtil 12%: reg-staged A chain
// load->wait->cvt->write sat INSIDE the barrier pair, exposing L2 latency every
// K-step). T14 graft on the proven 2-barrier skeleton:
//   - A(t+1) fp32 loads ISSUED during tile t's MFMA phase (latency hidden);
//     cvt + ds_write stay between the barriers (cheap VALU).
//   - raw s_barrier + counted waits (NOT __syncthreads, which drains vmcnt(0)
//     and would kill the in-flight A prefetch):
//       lgkmcnt(0); barrier                   // sync1: ds_reads delivered
//       gload16 B(t) x4; FENCE; cvt+write; issue A(t+1) x8
//       vmcnt(8) [t<15, keeps A(t+1) in flight; vmcnt(0) at t=15]; lgkmcnt(0)
//       barrier                               // sync2: B landed, writes visible
//       ds_read + 32 MFMA                     // A(t+1) flies under this
//   - FENCE (empty asm, memory clobber) pins issue order B(t) older than
//     A(t+1) so vmcnt(8) provably retires exactly B(t).
// Compiler's own waitcnt covers the A-reg consumption (it models
// global_load_lds in vmcnt bookkeeping — m97 relied on this).
// LDS layout + XOR swizzle identical to R6 (verified). 32KB -> 4 blocks/CU.
// ---------------------------------------------------------------------------
__global__ __launch_bounds__(256) void gemm_kernel(
    const float* __restrict__ x,             // [B][S][DIN] fp32
    const unsigned short* __restrict__ mw,   // [B][DOUT][DIN] bf16
    const float* __restrict__ mb,            // [B][DOUT] fp32
    float* __restrict__ out)                 // [B][S][DOUT] fp32
{
    __shared__ __align__(16) unsigned short sA[128 * 64];  // 16 KB
    __shared__ __align__(16) unsigned short sB[128 * 64];  // 16 KB

    const int tid  = threadIdx.x;
    const int wave = tid >> 6;
    const int lane = tid & 63;
    const int b    = blockIdx.x;          // batch -> XCD (id % 8 == b)
    const int tileN = blockIdx.y * 128;   // over DOUT
    const int tileM = blockIdx.z * 128;   // over S

    const float*          Ag = x  + (long)b * SS * DIN;
    const unsigned short* Bg = mw + (long)b * DOUT * DIN;

    const int q     = lane >> 4;     // quad 0..3
    const int r16   = lane & 15;
    const int mBase = 64 * (wave >> 1);
    const int nBase = 64 * (wave & 1);

    // staging: each wave owns 4 chunks of 8 rows x 64 cols for A and B
    const int sRow   = lane >> 3;                    // 0..7 row within chunk
    const int sColSw = (((lane & 7) ^ sRow) * 8);    // XOR-swizzled source column

    // hoisted loop-invariant source/dest addresses
    const float* aSrc[4]; const unsigned short* bSrc[4];
    unsigned short* aDst[4]; unsigned short* bDst[4];
    #pragma unroll
    for (int c = 0; c < 4; ++c) {
        const int chunk = wave * 4 + c;              // 0..15
        const int row   = chunk * 8 + sRow;          // 0..127
        aSrc[c] = Ag + (long)(tileM + row) * DIN + sColSw;
        bSrc[c] = Bg + (long)(tileN + row) * DIN + sColSw;
        aDst[c] = &sA[chunk * 512 + lane * 8];       // explicit per-lane 16B slot
        bDst[c] = &sB[chunk * 512];                  // gload_lds: wave base + lane*16
    }

    // reader: XOR-swizzled 16B-group offsets for the two kk halves (invariant)
    const int swz  = r16 & 7;
    const int colK0 = ((q)     ^ swz) * 8;           // kk = 0..31  (group q)
    const int colK1 = ((q + 4) ^ swz) * 8;           // kk = 32..63 (group q+4)

    floatx4 acc[4][4];
    #pragma unroll
    for (int mi = 0; mi < 4; ++mi)
        #pragma unroll
        for (int ni = 0; ni < 4; ++ni)
            acc[mi][ni] = (floatx4){0.f, 0.f, 0.f, 0.f};

    // prologue: A(0) into regs
    float4 aReg[4][2];
    #pragma unroll
    for (int c = 0; c < 4; ++c) {
        aReg[c][0] = *(const float4*)(aSrc[c]);
        aReg[c][1] = *(const float4*)(aSrc[c] + 4);
    }

    #pragma unroll
    for (int t = 0; t < 16; ++t) {                   // k0 = 64*t, fully unrolled
        // sync1: all waves' ds_reads of the previous tile are delivered
        asm volatile("s_waitcnt lgkmcnt(0)" ::: "memory");
        __builtin_amdgcn_s_barrier();

        // B(t): async global->LDS (imm offset 128*t bytes <= 1920)
        #pragma unroll
        for (int c = 0; c < 4; ++c)
            gload16(bSrc[c] + 64 * t, bDst[c]);

        asm volatile("" ::: "memory");   // pin order: B(t) older than A(t+1)

        // A(t): cvt from regs -> LDS (compiler inserts counted vmcnt for aReg)
        #pragma unroll
        for (int c = 0; c < 4; ++c) {
            float4 u = aReg[c][0], v = aReg[c][1];
            uint4 o;
            o.x = pk2(u.x, u.y); o.y = pk2(u.z, u.w);
            o.z = pk2(v.x, v.y); o.w = pk2(v.z, v.w);
            *(uint4*)aDst[c] = o;
        }

        // issue A(t+1) early — flies under the MFMA phase below
        if (t < 15) {
            #pragma unroll
            for (int c = 0; c < 4; ++c) {
                aReg[c][0] = *(const float4*)(aSrc[c] + 64 * (t + 1));
                aReg[c][1] = *(const float4*)(aSrc[c] + 64 * (t + 1) + 4);
            }
        }

        // sync2: B(t) landed (keep A(t+1) in flight), own ds_writes visible
        if (t < 15) { asm volatile("s_waitcnt vmcnt(8)"  ::: "memory"); }
        else        { asm volatile("s_waitcnt vmcnt(0)"  ::: "memory"); }
        asm volatile("s_waitcnt lgkmcnt(0)" ::: "memory");
        __builtin_amdgcn_s_barrier();

        #pragma unroll
        for (int kh = 0; kh < 2; ++kh) {
            const int col = kh ? colK1 : colK0;
            bf16x8 af[4], bfv[4];
            #pragma unroll
            for (int i = 0; i < 4; ++i)
                af[i] = *(const bf16x8*)&sA[(mBase + 16 * i + r16) * 64 + col];
            #pragma unroll
            for (int i = 0; i < 4; ++i)
                bfv[i] = *(const bf16x8*)&sB[(nBase + 16 * i + r16) * 64 + col];
            #pragma unroll
            for (int mi = 0; mi < 4; ++mi)
                #pragma unroll
                for (int ni = 0; ni < 4; ++ni)
                    acc[mi][ni] = __builtin_amdgcn_mfma_f32_16x16x32_bf16(
                        af[mi], bfv[ni], acc[mi][ni], 0, 0, 0);
        }
    }

    // epilogue: C[m][n] = acc + mixed_b[b][n]
    float bv[4];
    #pragma unroll
    for (int ni = 0; ni < 4; ++ni)
        bv[ni] = mb[b * DOUT + tileN + nBase + 16 * ni + r16];

    #pragma unroll
    for (int mi = 0; mi < 4; ++mi) {
        #pragma unroll
        for (int rr = 0; rr < 4; ++rr) {
            const int row = tileM + mBase + 16 * mi + q * 4 + rr;
            float* orow = out + (long)b * SS * DOUT + (long)row * DOUT;
            #pragma unroll
            for (int ni = 0; ni < 4; ++ni)
                orow[tileN + nBase + 16 * ni + r16] = acc[mi][ni][rr] + bv[ni];
        }
    }
}

extern "C" void kernel_launch(void* const* d_in, const int* in_sizes, int n_in,
                              void* d_out, int out_size, void* d_ws, size_t ws_size,
                              hipStream_t stream) {
    const float* x    = (const float*)d_in[0];   // [8,2048,1024]
    const float* p    = (const float*)d_in[1];   // [8,16]
    const float* w    = (const float*)d_in[2];   // [16,1024,1024]
    const float* bias = (const float*)d_in[3];   // [16,1024]
    float* out = (float*)d_out;                  // [8,2048,1024]

    // workspace layout: mixed_w bf16 (16 MiB) | mixed_b fp32 (32 KiB)
    unsigned short* mw = (unsigned short*)d_ws;
    float*          mb = (float*)((char*)d_ws + (size_t)16777216);

    prep_kernel<<<dim3(2080), 256, 0, stream>>>(p, w, bias, mw, mb);

    dim3 ggrid(BB, DOUT / 128, SS / 128);        // (8,8,16) = 1024 blocks
    gemm_kernel<<<ggrid, 256, 0, stream>>>(x, mw, mb, out);
}